// Round 14
// baseline (248.532 us; speedup 1.0000x reference)
//
#include <hip/hip_runtime.h>

#define NV 16384
#define BROWS 16          // L rows per block
#define JT 512            // j-tile width (floats): 2 KB burst per row-visit
#define NT (NV / JT)      // 32 tiles
#define THREADS 256

typedef const __attribute__((address_space(1))) void* as1_ptr;
typedef __attribute__((address_space(3))) void* as3_ptr;

__device__ __forceinline__ void gload_lds16(const float* g, float* l) {
  __builtin_amdgcn_global_load_lds((as1_ptr)g, (as3_ptr)l, 16, 0, 0);
}

#define FENCE asm volatile("" ::: "memory")
#define WAITV(n) asm volatile("s_waitcnt vmcnt(" #n ")" ::: "memory")

__global__ __launch_bounds__(THREADS, 2) void lap_loss_kernel(
    const float* __restrict__ x, const float* __restrict__ L,
    float* __restrict__ out) {
  __shared__ float lbuf[2][BROWS][JT];  // 2 x 32 KB double buffer

  const int lane = threadIdx.x & 63;
  const int w    = threadIdx.x >> 6;     // wave id == batch index b
  const size_t i0 = (size_t)blockIdx.x * BROWS;

  // j-phase rotation (R12 win): decorrelate the j-window across blocks.
  const int phase = (int)(blockIdx.x & (NT - 1));

  // wave w stages rows i0+4w .. i0+4w+3, two 1 KB chunks per row per tile
  const float* gL[4];
#pragma unroll
  for (int r = 0; r < 4; ++r)
    gL[r] = L + (i0 + 4 * w + r) * NV + lane * 4;

  // wave w's x stream: batch w, lane owns j-quad 4*lane within each half-tile
  const float* gx = x + (size_t)w * NV * 3 + lane * 12;

  float acc[BROWS][3];
#pragma unroll
  for (int r = 0; r < BROWS; ++r)
#pragma unroll
    for (int d = 0; d < 3; ++d) acc[r][d] = 0.f;

  // ---- prologue: x(TI(0)) both halves, then the 8 gl_lds for tile TI(0) ----
  const size_t j0 = (size_t)phase * JT;
  float4 xa0 = *(const float4*)(gx + j0 * 3 + 0);
  float4 xa1 = *(const float4*)(gx + j0 * 3 + 4);
  float4 xa2 = *(const float4*)(gx + j0 * 3 + 8);
  float4 xb0 = *(const float4*)(gx + (j0 + 256) * 3 + 0);
  float4 xb1 = *(const float4*)(gx + (j0 + 256) * 3 + 4);
  float4 xb2 = *(const float4*)(gx + (j0 + 256) * 3 + 8);
  FENCE;
#pragma unroll
  for (int r = 0; r < 4; ++r) {
    gload_lds16(gL[r] + j0,       &lbuf[0][4 * w + r][0]);
    gload_lds16(gL[r] + j0 + 256, &lbuf[0][4 * w + r][256]);
  }
  FENCE;

#pragma unroll 1
  for (int t = 0; t < NT; ++t) {
    const int cur = t & 1;

    float4 na0, na1, na2, nb0, nb1, nb2;
    if (t + 1 < NT) {
      const size_t jn = (size_t)((t + 1 + phase) & (NT - 1)) * JT;
      // 1) gl_lds prefetch L(TI(t+1)) FIRST: 8 ops, 2 KB per row
#pragma unroll
      for (int r = 0; r < 4; ++r) {
        gload_lds16(gL[r] + jn,       &lbuf[cur ^ 1][4 * w + r][0]);
        gload_lds16(gL[r] + jn + 256, &lbuf[cur ^ 1][4 * w + r][256]);
      }
      FENCE;
      // 2) x(TI(t+1)) prefetch LAST -> youngest in the vmem queue
      na0 = *(const float4*)(gx + jn * 3 + 0);
      na1 = *(const float4*)(gx + jn * 3 + 4);
      na2 = *(const float4*)(gx + jn * 3 + 8);
      nb0 = *(const float4*)(gx + (jn + 256) * 3 + 0);
      nb1 = *(const float4*)(gx + (jn + 256) * 3 + 4);
      nb2 = *(const float4*)(gx + (jn + 256) * 3 + 8);
      FENCE;
      // 3) retire tile t's 14 ops (a full tile old -> no stall);
      //    keep tile t+1's 8 gl_lds + 6 x loads in flight
      WAITV(14);
    } else {
      WAITV(0);
    }
    __builtin_amdgcn_s_barrier();
    FENCE;

    // 4) compute tile TI(t): 16 rows x 24 FMAs per lane, batch w
    {
      const float xfA[12] = {xa0.x, xa0.y, xa0.z, xa0.w,
                             xa1.x, xa1.y, xa1.z, xa1.w,
                             xa2.x, xa2.y, xa2.z, xa2.w};
      const float xfB[12] = {xb0.x, xb0.y, xb0.z, xb0.w,
                             xb1.x, xb1.y, xb1.z, xb1.w,
                             xb2.x, xb2.y, xb2.z, xb2.w};
#pragma unroll
      for (int r = 0; r < BROWS; ++r) {
        float4 lv0 = *(const float4*)&lbuf[cur][r][lane * 4];
        float4 lv1 = *(const float4*)&lbuf[cur][r][256 + lane * 4];
        const float lf0[4] = {lv0.x, lv0.y, lv0.z, lv0.w};
        const float lf1[4] = {lv1.x, lv1.y, lv1.z, lv1.w};
#pragma unroll
        for (int jj = 0; jj < 4; ++jj)
#pragma unroll
          for (int d = 0; d < 3; ++d) {
            acc[r][d] = fmaf(lf0[jj], xfA[jj * 3 + d], acc[r][d]);
            acc[r][d] = fmaf(lf1[jj], xfB[jj * 3 + d], acc[r][d]);
          }
      }
    }

    FENCE;
    __builtin_amdgcn_s_barrier();  // all waves done reading lbuf[cur]
    FENCE;

    xa0 = na0; xa1 = na1; xa2 = na2;
    xb0 = nb0; xb1 = nb1; xb2 = nb2;
  }

  // ---- butterfly-reduce each (row,d) partial over 64 lanes, square ----
  float s = 0.f;
#pragma unroll
  for (int r = 0; r < BROWS; ++r)
#pragma unroll
    for (int d = 0; d < 3; ++d) {
      float v = acc[r][d];
#pragma unroll
      for (int off = 32; off > 0; off >>= 1)
        v += __shfl_xor(v, off, 64);
      s += v * v;
    }

  if (lane == 0) atomicAdd(&out[w], s);  // wave w owns batch w
}

extern "C" void kernel_launch(void* const* d_in, const int* in_sizes, int n_in,
                              void* d_out, int out_size, void* d_ws, size_t ws_size,
                              hipStream_t stream) {
  const float* x = (const float*)d_in[0];
  const float* L = (const float*)d_in[1];
  float* out = (float*)d_out;

  // Harness poisons d_out with 0xAA and never re-poisons between replays.
  hipMemsetAsync(out, 0, out_size * sizeof(float), stream);

  const int nblocks = NV / BROWS;  // 1024 blocks; 2 resident/CU, 2 rounds
  lap_loss_kernel<<<nblocks, THREADS, 0, stream>>>(x, L, out);
}

// Round 15
// 196.598 us; speedup vs baseline: 1.2642x; 1.2642x over previous
//
#include <hip/hip_runtime.h>

#define NV 16384
#define BROWS 32          // L rows per block
#define JT 256            // j-tile width (floats); tile = 32 KB
#define NT (NV / JT)      // 64 tiles
#define THREADS 256

typedef const __attribute__((address_space(1))) void* as1_ptr;
typedef __attribute__((address_space(3))) void* as3_ptr;

// aux=2 -> CPol NT (non-temporal, gfx940+ encoding): L streams once, never
// reused -> don't let it evict x from L2/L3. Policy bit only; no semantics.
__device__ __forceinline__ void gload_lds16_nt(const float* g, float* l) {
  __builtin_amdgcn_global_load_lds((as1_ptr)g, (as3_ptr)l, 16, 0, 2);
}

#define FENCE asm volatile("" ::: "memory")
#define WAITV(n) asm volatile("s_waitcnt vmcnt(" #n ")" ::: "memory")

__global__ __launch_bounds__(THREADS, 2) void lap_loss_kernel(
    const float* __restrict__ x, const float* __restrict__ L,
    float* __restrict__ out) {
  __shared__ float lbuf[2][BROWS][JT];  // 2 x 32 KB double buffer

  const int lane = threadIdx.x & 63;
  const int w    = threadIdx.x >> 6;     // wave id == batch index b
  const size_t i0 = (size_t)blockIdx.x * BROWS;

  // j-phase rotation (R12 win): decorrelate the j-window (-> HBM channel
  // subset) across blocks; without it the whole chip sweeps j in lockstep.
  const int phase = (int)(blockIdx.x & (NT - 1));

  // wave w stages rows i0+8w .. i0+8w+7; lane covers 16B of each row
  const float* gL[8];
#pragma unroll
  for (int r = 0; r < 8; ++r)
    gL[r] = L + (i0 + 8 * w + r) * NV + lane * 4;

  // wave w's x stream: x[w][j][d], lane owns j-quad 4*lane (48B)
  const float* gx = x + (size_t)w * NV * 3 + lane * 12;

  float acc[BROWS][3];
#pragma unroll
  for (int r = 0; r < BROWS; ++r)
#pragma unroll
    for (int d = 0; d < 3; ++d) acc[r][d] = 0.f;

  // ---- prologue: x(TI(0)) regs, then the 8 gl_lds for tile TI(0) ----
  const size_t j0 = (size_t)phase * JT;
  float4 xc0 = *(const float4*)(gx + j0 * 3 + 0);
  float4 xc1 = *(const float4*)(gx + j0 * 3 + 4);
  float4 xc2 = *(const float4*)(gx + j0 * 3 + 8);
  FENCE;
#pragma unroll
  for (int r = 0; r < 8; ++r)
    gload_lds16_nt(gL[r] + j0, &lbuf[0][8 * w + r][0]);
  FENCE;

#pragma unroll 1
  for (int t = 0; t < NT; ++t) {
    const int cur = t & 1;

    float4 xn0, xn1, xn2;
    if (t + 1 < NT) {
      const size_t jn = (size_t)((t + 1 + phase) & (NT - 1)) * JT;
      // 1) gl_lds prefetch L(TI(t+1)) FIRST (older than the x prefetch)
#pragma unroll
      for (int r = 0; r < 8; ++r)
        gload_lds16_nt(gL[r] + jn, &lbuf[cur ^ 1][8 * w + r][0]);
      FENCE;
      // 2) x(TI(t+1)) prefetch LAST -> youngest in the vmem queue
      const float* gxn = gx + jn * 3;
      xn0 = *(const float4*)(gxn + 0);
      xn1 = *(const float4*)(gxn + 4);
      xn2 = *(const float4*)(gxn + 8);
      FENCE;
      // 3) retire L(t)x8 + x(t)x3 (a full tile old -> no stall);
      //    keep L(t+1)x8 + x(t+1)x3 = 11 in flight across barrier+compute
      WAITV(11);
    } else {
      WAITV(0);
    }
    __builtin_amdgcn_s_barrier();
    FENCE;

    // 4) compute tile TI(t): 32 rows x 12 FMAs per lane-j-quad, batch w
    {
      const float xf[12] = {xc0.x, xc0.y, xc0.z, xc0.w,
                            xc1.x, xc1.y, xc1.z, xc1.w,
                            xc2.x, xc2.y, xc2.z, xc2.w};
#pragma unroll
      for (int r = 0; r < BROWS; ++r) {
        float4 lv = *(const float4*)&lbuf[cur][r][lane * 4];
        const float lf[4] = {lv.x, lv.y, lv.z, lv.w};
#pragma unroll
        for (int jj = 0; jj < 4; ++jj)
#pragma unroll
          for (int d = 0; d < 3; ++d)
            acc[r][d] = fmaf(lf[jj], xf[jj * 3 + d], acc[r][d]);
      }
    }

    FENCE;
    __builtin_amdgcn_s_barrier();  // all waves done reading lbuf[cur]
    FENCE;

    xc0 = xn0; xc1 = xn1; xc2 = xn2;
  }

  // ---- butterfly-reduce each (row,d) partial over 64 lanes, square ----
  float s = 0.f;
#pragma unroll
  for (int r = 0; r < BROWS; ++r)
#pragma unroll
    for (int d = 0; d < 3; ++d) {
      float v = acc[r][d];
#pragma unroll
      for (int off = 32; off > 0; off >>= 1)
        v += __shfl_xor(v, off, 64);
      s += v * v;
    }

  if (lane == 0) atomicAdd(&out[w], s);  // wave w owns batch w
}

extern "C" void kernel_launch(void* const* d_in, const int* in_sizes, int n_in,
                              void* d_out, int out_size, void* d_ws, size_t ws_size,
                              hipStream_t stream) {
  const float* x = (const float*)d_in[0];
  const float* L = (const float*)d_in[1];
  float* out = (float*)d_out;

  // Harness poisons d_out with 0xAA and never re-poisons between replays.
  hipMemsetAsync(out, 0, out_size * sizeof(float), stream);

  const int nblocks = NV / BROWS;  // 512 blocks = exactly 2 resident per CU
  lap_loss_kernel<<<nblocks, THREADS, 0, stream>>>(x, L, out);
}